// Round 2
// baseline (862.223 us; speedup 1.0000x reference)
//
#include <hip/hip_runtime.h>
#include <hip/hip_bf16.h>
#include <cmath>

#define S_ 2048
#define D_ 1024
#define H_ 16
#define HD_ 64

typedef __attribute__((ext_vector_type(4))) float f32x4;
typedef __attribute__((ext_vector_type(8))) short bf16x8;
typedef __attribute__((ext_vector_type(4))) short bf16x4;

__device__ __forceinline__ short f2bf(float f) {
    union { float f; unsigned u; } x; x.f = f;
    unsigned r = x.u + 0x7fffu + ((x.u >> 16) & 1u);  // RNE
    return (short)(r >> 16);
}

// C[m,n] = sum_k A[m,k]*W[n,k] + bias[n];  A: MxK fp32, W: NxK fp32 (torch Linear NT layout).
// 64x64 tile, 4 waves, BK=32 (one 16x16x32 MFMA k-step). fp32->bf16 at LDS store.
// LDS rows are 64B (32 bf16); 16B-slot swizzle: slot' = slot ^ ((row>>1)&3) -> <=2-way conflicts.
__global__ __launch_bounds__(256) void gemm_nt_bias(
    const float* __restrict__ A, const float* __restrict__ W,
    const float* __restrict__ bias, float* __restrict__ C,
    int M, int N, int K)
{
    __shared__ short As[64 * 32];
    __shared__ short Bs[64 * 32];
    const int t = threadIdx.x;
    const int lane = t & 63;
    const int wave = t >> 6;
    const int m0 = blockIdx.y * 64;
    const int n0 = blockIdx.x * 64;
    const int wr = (wave >> 1) * 32;   // wave's 32x32 quadrant
    const int wc = (wave & 1) * 32;
    const int fr = lane & 15;
    const int chunk = lane >> 4;       // which 8-wide k-chunk of the 32-k tile

    f32x4 acc[2][2] = {};

    for (int kt = 0; kt < K; kt += 32) {
        __syncthreads();
        #pragma unroll
        for (int p = 0; p < 2; ++p) {
            int i = t + p * 256;            // float4 index over 64x32 tile
            int row = i >> 3;
            int col = (i & 7) << 2;
            int bb = col << 1;              // byte offset within 64B row
            int sb = (row << 6) + ((((bb >> 4) ^ ((row >> 1) & 3)) << 4) | (bb & 15));
            f32x4 va = *(const f32x4*)(A + (size_t)(m0 + row) * K + kt + col);
            bf16x4 ha;
            ha[0] = f2bf(va[0]); ha[1] = f2bf(va[1]); ha[2] = f2bf(va[2]); ha[3] = f2bf(va[3]);
            *(bf16x4*)((char*)As + sb) = ha;
            f32x4 vb = *(const f32x4*)(W + (size_t)(n0 + row) * K + kt + col);
            bf16x4 hb;
            hb[0] = f2bf(vb[0]); hb[1] = f2bf(vb[1]); hb[2] = f2bf(vb[2]); hb[3] = f2bf(vb[3]);
            *(bf16x4*)((char*)Bs + sb) = hb;
        }
        __syncthreads();
        bf16x8 af[2], bfr[2];
        #pragma unroll
        for (int mb = 0; mb < 2; ++mb) {
            int row = wr + mb * 16 + fr;
            int sb = (row << 6) + ((chunk ^ ((row >> 1) & 3)) << 4);
            af[mb] = *(const bf16x8*)((const char*)As + sb);
        }
        #pragma unroll
        for (int nb = 0; nb < 2; ++nb) {
            int row = wc + nb * 16 + fr;
            int sb = (row << 6) + ((chunk ^ ((row >> 1) & 3)) << 4);
            bfr[nb] = *(const bf16x8*)((const char*)Bs + sb);
        }
        #pragma unroll
        for (int mb = 0; mb < 2; ++mb)
            #pragma unroll
            for (int nb = 0; nb < 2; ++nb)
                acc[mb][nb] = __builtin_amdgcn_mfma_f32_16x16x32_bf16(
                    af[mb], bfr[nb], acc[mb][nb], 0, 0, 0);
    }

    #pragma unroll
    for (int mb = 0; mb < 2; ++mb) {
        #pragma unroll
        for (int nb = 0; nb < 2; ++nb) {
            int row = m0 + wr + mb * 16 + (lane >> 4) * 4;
            int col = n0 + wc + nb * 16 + (lane & 15);
            float bv = bias[col];
            #pragma unroll
            for (int r = 0; r < 4; ++r)
                C[(size_t)(row + r) * N + col] = acc[mb][nb][r] + bv;
        }
    }
}

// fp32 flash attention, causal. Block = 256 threads handles one (b,h,64-row q-tile).
// Thread (qi = t>>2, c = t&3): owns q-row qi, score columns {c*16..}, O dims [c*16, c*16+16).
// SQ doubles as the P (exp-scores) tile after qreg extraction.
__global__ __launch_bounds__(256) void attn_fwd(
    const float* __restrict__ Q, const float* __restrict__ K,
    const float* __restrict__ V, float* __restrict__ O)
{
    __shared__ float SQ[64][68];
    __shared__ float SK[64][68];
    __shared__ float SV[64][68];

    const int t = threadIdx.x;
    const int qi = t >> 2;
    const int c = t & 3;
    const int c16 = c * 16;
    const int qt = blockIdx.x;
    const int bh = blockIdx.y;
    const int b = bh >> 4;
    const int h = bh & 15;
    const int q0 = qt * 64;
    const size_t base = (size_t)b * S_ * D_ + (size_t)h * HD_;

    // stage Q tile (pre-scaled by 1/sqrt(HD) = 1/8)
    #pragma unroll
    for (int p = 0; p < 4; ++p) {
        int i = t + p * 256;
        int row = i >> 4;
        int col = (i & 15) << 2;
        f32x4 v = *(const f32x4*)(Q + base + (size_t)(q0 + row) * D_ + col);
        v *= 0.125f;
        *(f32x4*)&SQ[row][col] = v;
    }
    __syncthreads();
    float qreg[64];
    #pragma unroll
    for (int d = 0; d < 64; ++d) qreg[d] = SQ[qi][d];

    float mrow = -INFINITY, l = 0.f;
    float Ob[16];
    #pragma unroll
    for (int d = 0; d < 16; ++d) Ob[d] = 0.f;

    for (int kt = 0; kt <= qt; ++kt) {
        const int k0 = kt * 64;
        __syncthreads();  // protect SK/SV/SQ(P) from previous iteration's readers
        #pragma unroll
        for (int p = 0; p < 4; ++p) {
            int i = t + p * 256;
            int row = i >> 4;
            int col = (i & 15) << 2;
            f32x4 kv = *(const f32x4*)(K + base + (size_t)(k0 + row) * D_ + col);
            f32x4 vv = *(const f32x4*)(V + base + (size_t)(k0 + row) * D_ + col);
            *(f32x4*)&SK[row][col] = kv;
            *(f32x4*)&SV[row][col] = vv;
        }
        __syncthreads();

        // scores for 16 keys (c-staggered to spread LDS banks)
        float s[16];
        float tmax = -INFINITY;
        #pragma unroll
        for (int j = 0; j < 16; ++j) {
            const int kj = c16 + ((j + c) & 15);
            float acc = 0.f;
            #pragma unroll
            for (int d4 = 0; d4 < 16; ++d4) {
                f32x4 kv = *(const f32x4*)&SK[kj][d4 << 2];
                acc += qreg[d4 * 4 + 0] * kv[0];
                acc += qreg[d4 * 4 + 1] * kv[1];
                acc += qreg[d4 * 4 + 2] * kv[2];
                acc += qreg[d4 * 4 + 3] * kv[3];
            }
            if (k0 + kj > q0 + qi) acc = -INFINITY;  // causal
            s[j] = acc;
            tmax = fmaxf(tmax, acc);
        }
        tmax = fmaxf(tmax, __shfl_xor(tmax, 1));
        tmax = fmaxf(tmax, __shfl_xor(tmax, 2));
        const float mnew = fmaxf(mrow, tmax);
        const float rescale = __expf(mrow - mnew);   // 0 on first tile (-inf - finite)
        float psum = 0.f;
        #pragma unroll
        for (int j = 0; j < 16; ++j) {
            const int kj = c16 + ((j + c) & 15);
            float p = __expf(s[j] - mnew);
            SQ[qi][kj] = p;                          // P tile
            psum += p;
        }
        psum += __shfl_xor(psum, 1);
        psum += __shfl_xor(psum, 2);
        l = l * rescale + psum;
        mrow = mnew;
        #pragma unroll
        for (int d = 0; d < 16; ++d) Ob[d] *= rescale;
        __syncthreads();  // P visible to the whole row-quad

        #pragma unroll 4
        for (int kj = 0; kj < 64; ++kj) {
            const float pj = SQ[qi][kj];
            const f32x4 v0 = *(const f32x4*)&SV[kj][c16 + 0];
            const f32x4 v1 = *(const f32x4*)&SV[kj][c16 + 4];
            const f32x4 v2 = *(const f32x4*)&SV[kj][c16 + 8];
            const f32x4 v3 = *(const f32x4*)&SV[kj][c16 + 12];
            Ob[0]  += pj * v0[0]; Ob[1]  += pj * v0[1]; Ob[2]  += pj * v0[2]; Ob[3]  += pj * v0[3];
            Ob[4]  += pj * v1[0]; Ob[5]  += pj * v1[1]; Ob[6]  += pj * v1[2]; Ob[7]  += pj * v1[3];
            Ob[8]  += pj * v2[0]; Ob[9]  += pj * v2[1]; Ob[10] += pj * v2[2]; Ob[11] += pj * v2[3];
            Ob[12] += pj * v3[0]; Ob[13] += pj * v3[1]; Ob[14] += pj * v3[2]; Ob[15] += pj * v3[3];
        }
    }

    const float rl = 1.0f / l;
    float* op = O + base + (size_t)(q0 + qi) * D_ + c16;
    #pragma unroll
    for (int d4 = 0; d4 < 4; ++d4) {
        f32x4 v;
        v[0] = Ob[d4 * 4 + 0] * rl; v[1] = Ob[d4 * 4 + 1] * rl;
        v[2] = Ob[d4 * 4 + 2] * rl; v[3] = Ob[d4 * 4 + 3] * rl;
        *(f32x4*)(op + d4 * 4) = v;
    }
}

extern "C" void kernel_launch(void* const* d_in, const int* in_sizes, int n_in,
                              void* d_out, int out_size, void* d_ws, size_t ws_size,
                              hipStream_t stream)
{
    const float* x  = (const float*)d_in[0];
    // d_in[1] = mask: causal mask computed analytically, unused
    const float* Wq = (const float*)d_in[2];
    const float* bq = (const float*)d_in[3];
    const float* Wk = (const float*)d_in[4];
    const float* bk = (const float*)d_in[5];
    const float* Wv = (const float*)d_in[6];
    const float* bv = (const float*)d_in[7];
    const float* Wo = (const float*)d_in[8];
    const float* bo = (const float*)d_in[9];
    float* out = (float*)d_out;

    const int M = 2 * S_;  // 4096 rows
    float* Qw = (float*)d_ws;                      // 16 MB
    float* Kw = Qw + (size_t)M * D_;               // 16 MB
    float* Vw = Kw + (size_t)M * D_;               // 16 MB  (total 48 MB of ws)

    dim3 gblk(256);
    dim3 ggrid(D_ / 64, M / 64);
    gemm_nt_bias<<<ggrid, gblk, 0, stream>>>(x, Wq, bq, Qw, M, D_, D_);
    gemm_nt_bias<<<ggrid, gblk, 0, stream>>>(x, Wk, bk, Kw, M, D_, D_);
    gemm_nt_bias<<<ggrid, gblk, 0, stream>>>(x, Wv, bv, Vw, M, D_, D_);

    // ctx aliases Qw: each attn block reads only its own (b,h,qtile) Q slice
    // (into registers, during its stage phase) before writing ctx to the same slice.
    dim3 agrid(S_ / 64, 2 * H_);
    attn_fwd<<<agrid, gblk, 0, stream>>>(Qw, Kw, Vw, Qw);

    gemm_nt_bias<<<ggrid, gblk, 0, stream>>>(Qw, Wo, bo, out, M, D_, D_);
}

// Round 4
// 339.554 us; speedup vs baseline: 2.5393x; 2.5393x over previous
//
#include <hip/hip_runtime.h>
#include <hip/hip_bf16.h>
#include <cmath>

#define S_ 2048
#define D_ 1024
#define H_ 16
#define HD_ 64

typedef __attribute__((ext_vector_type(4))) float f32x4;
typedef __attribute__((ext_vector_type(8))) short bf16x8;
typedef __attribute__((ext_vector_type(4))) short bf16x4;

__device__ __forceinline__ short f2bf(float f) {
    union { float f; unsigned u; } x; x.f = f;
    unsigned r = x.u + 0x7fffu + ((x.u >> 16) & 1u);  // RNE
    return (short)(r >> 16);
}

// ---------------- GEMM (unchanged from baseline) ----------------
// C[m,n] = sum_k A[m,k]*W[n,k] + bias[n];  A: MxK fp32, W: NxK fp32.
__global__ __launch_bounds__(256) void gemm_nt_bias(
    const float* __restrict__ A, const float* __restrict__ W,
    const float* __restrict__ bias, float* __restrict__ C,
    int M, int N, int K)
{
    __shared__ short As[64 * 32];
    __shared__ short Bs[64 * 32];
    const int t = threadIdx.x;
    const int lane = t & 63;
    const int wave = t >> 6;
    const int m0 = blockIdx.y * 64;
    const int n0 = blockIdx.x * 64;
    const int wr = (wave >> 1) * 32;
    const int wc = (wave & 1) * 32;
    const int fr = lane & 15;
    const int chunk = lane >> 4;

    f32x4 acc[2][2] = {};

    for (int kt = 0; kt < K; kt += 32) {
        __syncthreads();
        #pragma unroll
        for (int p = 0; p < 2; ++p) {
            int i = t + p * 256;
            int row = i >> 3;
            int col = (i & 7) << 2;
            int bb = col << 1;
            int sb = (row << 6) + ((((bb >> 4) ^ ((row >> 1) & 3)) << 4) | (bb & 15));
            f32x4 va = *(const f32x4*)(A + (size_t)(m0 + row) * K + kt + col);
            bf16x4 ha;
            ha[0] = f2bf(va[0]); ha[1] = f2bf(va[1]); ha[2] = f2bf(va[2]); ha[3] = f2bf(va[3]);
            *(bf16x4*)((char*)As + sb) = ha;
            f32x4 vb = *(const f32x4*)(W + (size_t)(n0 + row) * K + kt + col);
            bf16x4 hb;
            hb[0] = f2bf(vb[0]); hb[1] = f2bf(vb[1]); hb[2] = f2bf(vb[2]); hb[3] = f2bf(vb[3]);
            *(bf16x4*)((char*)Bs + sb) = hb;
        }
        __syncthreads();
        bf16x8 af[2], bfr[2];
        #pragma unroll
        for (int mb = 0; mb < 2; ++mb) {
            int row = wr + mb * 16 + fr;
            int sb = (row << 6) + ((chunk ^ ((row >> 1) & 3)) << 4);
            af[mb] = *(const bf16x8*)((const char*)As + sb);
        }
        #pragma unroll
        for (int nb = 0; nb < 2; ++nb) {
            int row = wc + nb * 16 + fr;
            int sb = (row << 6) + ((chunk ^ ((row >> 1) & 3)) << 4);
            bfr[nb] = *(const bf16x8*)((const char*)Bs + sb);
        }
        #pragma unroll
        for (int mb = 0; mb < 2; ++mb)
            #pragma unroll
            for (int nb = 0; nb < 2; ++nb)
                acc[mb][nb] = __builtin_amdgcn_mfma_f32_16x16x32_bf16(
                    af[mb], bfr[nb], acc[mb][nb], 0, 0, 0);
    }

    #pragma unroll
    for (int mb = 0; mb < 2; ++mb) {
        #pragma unroll
        for (int nb = 0; nb < 2; ++nb) {
            int row = m0 + wr + mb * 16 + (lane >> 4) * 4;
            int col = n0 + wc + nb * 16 + (lane & 15);
            float bv = bias[col];
            #pragma unroll
            for (int r = 0; r < 4; ++r)
                C[(size_t)(row + r) * N + col] = acc[mb][nb][r] + bv;
        }
    }
}

// ---------------- MFMA flash attention ----------------
// Block = 256 thr (4 waves); one (b,h,64-row q-tile). Wave w owns q-rows
// [w*16, w*16+16) x full 64-col K-tile -> softmax never crosses waves.
// LDS tiles are bf16 [64 rows][128B = 8 x 16B slots], slot-XOR-swizzled.
// SQ/SK/SP swizzle: slot ^ (row&7)   (b128 frag reads: rows 0-15 -> 2-way, free)
// SVT   swizzle: slot ^ ((row>>1)&7) (keeps transposed b32 writes <=4-way)

// stage a 64x64 fp32 tile -> bf16 LDS, row-major, swizzled (slot ^ (row&7))
__device__ __forceinline__ void stage_tile64(const float* __restrict__ src,
                                             short* dst, float scale, int t) {
    #pragma unroll
    for (int p = 0; p < 2; ++p) {
        int id = t + p * 256;             // 512 slots = 64 rows x 8 slots
        int row = id >> 3, sl = id & 7;
        const float* s = src + (size_t)row * D_ + sl * 8;
        f32x4 a = *(const f32x4*)s;
        f32x4 b = *(const f32x4*)(s + 4);
        a *= scale; b *= scale;
        bf16x8 hv;
        hv[0] = f2bf(a[0]); hv[1] = f2bf(a[1]); hv[2] = f2bf(a[2]); hv[3] = f2bf(a[3]);
        hv[4] = f2bf(b[0]); hv[5] = f2bf(b[1]); hv[6] = f2bf(b[2]); hv[7] = f2bf(b[3]);
        *(bf16x8*)((char*)dst + row * 128 + ((sl ^ (row & 7)) << 4)) = hv;
    }
}

__global__ __launch_bounds__(256) void attn_fwd_mfma(
    const float* __restrict__ Q, const float* __restrict__ K,
    const float* __restrict__ V, float* __restrict__ O)
{
    __shared__ short SQ[64 * 64];
    __shared__ short SK[64 * 64];
    __shared__ short SVT[64 * 64];   // V^T: rows = d, cols = j
    __shared__ short SP[64 * 64];    // P:   rows = q, cols = j

    const int t = threadIdx.x;
    const int lane = t & 63;
    const int w = t >> 6;
    const int g = lane >> 4;          // 16-lane group
    const int fr = lane & 15;
    const int qt = blockIdx.x;
    const int bh = blockIdx.y;
    const int b = bh >> 4;
    const int h = bh & 15;
    const int q0 = qt * 64;
    const size_t base = (size_t)b * S_ * D_ + (size_t)h * HD_;

    stage_tile64(Q + base + (size_t)q0 * D_, SQ, 0.125f, t);  // scale folded in
    __syncthreads();

    f32x4 Oacc[4] = {};               // [nb over d][r]; row = w*16+g*4+r, col(d)=nb*16+fr
    float m4[4] = { -1e30f, -1e30f, -1e30f, -1e30f };
    float l4[4] = { 0.f, 0.f, 0.f, 0.f };
    const int qrow_base = w * 16 + g * 4;

    for (int kt = 0; kt <= qt; ++kt) {
        const int k0 = kt * 64;
        __syncthreads();              // prev iteration's PV reads of SK/SVT done
        stage_tile64(K + base + (size_t)k0 * D_, SK, 1.0f, t);
        // stage V^T: transpose-on-write, packed 2xbf16 per b32 store
        #pragma unroll
        for (int p = 0; p < 2; ++p) {
            int a_ = (t >> 4) + p * 16;          // j-pair index 0..31
            int d0 = (t & 15) * 4;
            const float* s0 = V + base + (size_t)(k0 + 2 * a_) * D_ + d0;
            f32x4 v0 = *(const f32x4*)s0;
            f32x4 v1 = *(const f32x4*)(s0 + D_);
            #pragma unroll
            for (int e = 0; e < 4; ++e) {
                int row = d0 + e;                // d
                int col = 2 * a_;                // j
                int sb = row * 128 + ((((col >> 3) ^ ((row >> 1) & 7))) << 4) + ((col & 7) << 1);
                unsigned pk = (unsigned)(unsigned short)f2bf(v0[e])
                            | ((unsigned)(unsigned short)f2bf(v1[e]) << 16);
                *(unsigned*)((char*)SVT + sb) = pk;
            }
        }
        __syncthreads();

        // ---- QK^T: S[q][kj], q = w*16.., kj = 0..63 ----
        f32x4 sacc[4] = {};
        #pragma unroll
        for (int ks = 0; ks < 2; ++ks) {
            int arow = w * 16 + fr;
            bf16x8 aq = *(const bf16x8*)((const char*)SQ + arow * 128 + (((g + ks * 4) ^ (arow & 7)) << 4));
            #pragma unroll
            for (int nb = 0; nb < 4; ++nb) {
                int brow = nb * 16 + fr;
                bf16x8 bk = *(const bf16x8*)((const char*)SK + brow * 128 + (((g + ks * 4) ^ (brow & 7)) << 4));
                sacc[nb] = __builtin_amdgcn_mfma_f32_16x16x32_bf16(aq, bk, sacc[nb], 0, 0, 0);
            }
        }
        // causal mask (only the diagonal tile needs it)
        if (kt == qt) {
            #pragma unroll
            for (int nb = 0; nb < 4; ++nb)
                #pragma unroll
                for (int r = 0; r < 4; ++r)
                    if (nb * 16 + fr > qrow_base + r) sacc[nb][r] = -1e30f;
        }

        // ---- online softmax (in-register, per-row state) ----
        float resc[4], ps[4];
        #pragma unroll
        for (int r = 0; r < 4; ++r) {
            float rm = fmaxf(fmaxf(sacc[0][r], sacc[1][r]), fmaxf(sacc[2][r], sacc[3][r]));
            rm = fmaxf(rm, __shfl_xor(rm, 1));
            rm = fmaxf(rm, __shfl_xor(rm, 2));
            rm = fmaxf(rm, __shfl_xor(rm, 4));
            rm = fmaxf(rm, __shfl_xor(rm, 8));
            float mn = fmaxf(m4[r], rm);
            resc[r] = __expf(m4[r] - mn);
            m4[r] = mn;
            ps[r] = 0.f;
        }
        #pragma unroll
        for (int nb = 0; nb < 4; ++nb) {
            #pragma unroll
            for (int r = 0; r < 4; ++r) {
                float pe = __expf(sacc[nb][r] - m4[r]);
                ps[r] += pe;
                int col = nb * 16 + fr;
                int row = qrow_base + r;
                int sb = row * 128 + ((((col >> 3) ^ (row & 7))) << 4) + ((col & 7) << 1);
                *(short*)((char*)SP + sb) = f2bf(pe);
            }
        }
        #pragma unroll
        for (int r = 0; r < 4; ++r) {
            float s = ps[r];
            s += __shfl_xor(s, 1);
            s += __shfl_xor(s, 2);
            s += __shfl_xor(s, 4);
            s += __shfl_xor(s, 8);
            l4[r] = l4[r] * resc[r] + s;
        }
        #pragma unroll
        for (int nb = 0; nb < 4; ++nb)
            #pragma unroll
            for (int r = 0; r < 4; ++r)
                Oacc[nb][r] *= resc[r];

        // ---- PV: O[q][d] += P[q][j] * V[j][d]  (B-frag from SVT rows=d) ----
        // SP rows for this wave were written by this wave only -> no barrier.
        #pragma unroll
        for (int ks = 0; ks < 2; ++ks) {
            int arow = w * 16 + fr;
            bf16x8 ap = *(const bf16x8*)((const char*)SP + arow * 128 + (((g + ks * 4) ^ (arow & 7)) << 4));
            #pragma unroll
            for (int nb = 0; nb < 4; ++nb) {
                int brow = nb * 16 + fr;   // d
                bf16x8 bv = *(const bf16x8*)((const char*)SVT + brow * 128 + (((g + ks * 4) ^ ((brow >> 1) & 7)) << 4));
                Oacc[nb] = __builtin_amdgcn_mfma_f32_16x16x32_bf16(ap, bv, Oacc[nb], 0, 0, 0);
            }
        }
    }

    // epilogue: normalize and store
    float rl[4];
    #pragma unroll
    for (int r = 0; r < 4; ++r) rl[r] = 1.0f / l4[r];
    #pragma unroll
    for (int nb = 0; nb < 4; ++nb) {
        #pragma unroll
        for (int r = 0; r < 4; ++r) {
            int row = qrow_base + r;
            int col = nb * 16 + fr;
            O[base + (size_t)(q0 + row) * D_ + col] = Oacc[nb][r] * rl[r];
        }
    }
}

extern "C" void kernel_launch(void* const* d_in, const int* in_sizes, int n_in,
                              void* d_out, int out_size, void* d_ws, size_t ws_size,
                              hipStream_t stream)
{
    const float* x  = (const float*)d_in[0];
    // d_in[1] = mask: causal mask computed analytically, unused
    const float* Wq = (const float*)d_in[2];
    const float* bq = (const float*)d_in[3];
    const float* Wk = (const float*)d_in[4];
    const float* bk = (const float*)d_in[5];
    const float* Wv = (const float*)d_in[6];
    const float* bv = (const float*)d_in[7];
    const float* Wo = (const float*)d_in[8];
    const float* bo = (const float*)d_in[9];
    float* out = (float*)d_out;

    const int M = 2 * S_;  // 4096 rows
    float* Qw = (float*)d_ws;                      // 16 MB
    float* Kw = Qw + (size_t)M * D_;               // 16 MB
    float* Vw = Kw + (size_t)M * D_;               // 16 MB  (total 48 MB of ws)

    dim3 gblk(256);
    dim3 ggrid(D_ / 64, M / 64);
    gemm_nt_bias<<<ggrid, gblk, 0, stream>>>(x, Wq, bq, Qw, M, D_, D_);
    gemm_nt_bias<<<ggrid, gblk, 0, stream>>>(x, Wk, bk, Kw, M, D_, D_);
    gemm_nt_bias<<<ggrid, gblk, 0, stream>>>(x, Wv, bv, Vw, M, D_, D_);

    // ctx aliases Qw: each attn block reads only its own (b,h,qtile) Q slice
    // (into SQ, in its prologue) before writing ctx back to the same slice.
    dim3 agrid(S_ / 64, 2 * H_);
    attn_fwd_mfma<<<agrid, gblk, 0, stream>>>(Qw, Kw, Vw, Qw);

    gemm_nt_bias<<<ggrid, gblk, 0, stream>>>(Qw, Wo, bo, out, M, D_, D_);
}

// Round 5
// 178.405 us; speedup vs baseline: 4.8329x; 1.9033x over previous
//
#include <hip/hip_runtime.h>
#include <hip/hip_bf16.h>
#include <cmath>

#define S_ 2048
#define D_ 1024
#define H_ 16
#define HD_ 64
#define NQT 32          // S_/64 q-tiles

typedef __attribute__((ext_vector_type(4))) float f32x4;
typedef __attribute__((ext_vector_type(8))) short bf16x8;
typedef __attribute__((ext_vector_type(4))) short bf16x4;

__device__ __forceinline__ short f2bf(float f) {
    union { float f; unsigned u; } x; x.f = f;
    unsigned r = x.u + 0x7fffu + ((x.u >> 16) & 1u);  // RNE
    return (short)(r >> 16);
}

// ---------------- fp32 -> bf16 converters (one-time) ----------------
__global__ __launch_bounds__(256) void cvt_f32_bf16(const float* __restrict__ src,
                                                    short* __restrict__ dst, int n8) {
    int id = blockIdx.x * 256 + threadIdx.x;
    if (id >= n8) return;
    const float* s = src + (size_t)id * 8;
    f32x4 a = *(const f32x4*)s;
    f32x4 b = *(const f32x4*)(s + 4);
    bf16x8 h;
    h[0] = f2bf(a[0]); h[1] = f2bf(a[1]); h[2] = f2bf(a[2]); h[3] = f2bf(a[3]);
    h[4] = f2bf(b[0]); h[5] = f2bf(b[1]); h[6] = f2bf(b[2]); h[7] = f2bf(b[3]);
    *(bf16x8*)(dst + (size_t)id * 8) = h;
}

__global__ __launch_bounds__(256) void cvt_w4(const float* __restrict__ w0, const float* __restrict__ w1,
                                              const float* __restrict__ w2, const float* __restrict__ w3,
                                              short* __restrict__ dst) {
    const float* src = (blockIdx.y == 0) ? w0 : (blockIdx.y == 1) ? w1 : (blockIdx.y == 2) ? w2 : w3;
    int id = blockIdx.x * 256 + threadIdx.x;          // 131072 per W
    const float* s = src + (size_t)id * 8;
    f32x4 a = *(const f32x4*)s;
    f32x4 b = *(const f32x4*)(s + 4);
    bf16x8 h;
    h[0] = f2bf(a[0]); h[1] = f2bf(a[1]); h[2] = f2bf(a[2]); h[3] = f2bf(a[3]);
    h[4] = f2bf(b[0]); h[5] = f2bf(b[1]); h[6] = f2bf(b[2]); h[7] = f2bf(b[3]);
    *(bf16x8*)(dst + (((size_t)blockIdx.y) << 20) + (size_t)id * 8) = h;
}

// ---------------- bf16 GEMM, 64x64 tile, templated epilogue ----------------
// C[m,n] = sum_k A[m,k]*W[n,k] + bias[n]; A,W bf16 row-major (NT).
#define EPI_F32        0   // fp32 row-major [M][N]
#define EPI_BF16       1   // bf16 row-major [M][N]
#define EPI_BF16_SCALE 2   // bf16 row-major, *0.125 (Q)
#define EPI_VT         3   // bf16 per-head transposed: Vt[(b*16+h)*64 + d][S_] (h == blockIdx.x)

template<int EPI>
__global__ __launch_bounds__(256) void gemm_bf16_nt(
    const short* __restrict__ A, const short* __restrict__ W,
    const float* __restrict__ bias, void* __restrict__ C,
    int M, int N, int K)
{
    __shared__ short As[64 * 32];
    __shared__ short Bs[64 * 32];
    const int t = threadIdx.x;
    const int lane = t & 63;
    const int wave = t >> 6;
    const int m0 = blockIdx.y * 64;
    const int n0 = blockIdx.x * 64;
    const int wr = (wave >> 1) * 32;
    const int wc = (wave & 1) * 32;
    const int fr = lane & 15;
    const int chunk = lane >> 4;      // 8-k chunk 0..3

    const int srow = t >> 2, ssl = t & 3;   // staging: 64 rows x 4 slots
    const int ssb = (srow << 6) + (((ssl ^ (srow & 3)) << 4));

    f32x4 acc[2][2] = {};

    for (int kt = 0; kt < K; kt += 32) {
        __syncthreads();
        *(bf16x8*)((char*)As + ssb) = *(const bf16x8*)(A + (size_t)(m0 + srow) * K + kt + ssl * 8);
        *(bf16x8*)((char*)Bs + ssb) = *(const bf16x8*)(W + (size_t)(n0 + srow) * K + kt + ssl * 8);
        __syncthreads();
        bf16x8 af[2], bfr[2];
        #pragma unroll
        for (int mb = 0; mb < 2; ++mb) {
            int row = wr + mb * 16 + fr;
            af[mb] = *(const bf16x8*)((const char*)As + (row << 6) + ((chunk ^ (row & 3)) << 4));
        }
        #pragma unroll
        for (int nb = 0; nb < 2; ++nb) {
            int row = wc + nb * 16 + fr;
            bfr[nb] = *(const bf16x8*)((const char*)Bs + (row << 6) + ((chunk ^ (row & 3)) << 4));
        }
        #pragma unroll
        for (int mb = 0; mb < 2; ++mb)
            #pragma unroll
            for (int nb = 0; nb < 2; ++nb)
                acc[mb][nb] = __builtin_amdgcn_mfma_f32_16x16x32_bf16(
                    af[mb], bfr[nb], acc[mb][nb], 0, 0, 0);
    }

    if constexpr (EPI == EPI_VT) {
        // transpose 64x64 tile in LDS, then coalesced bf16x8 stores to Vt.
        __shared__ short Cs[64 * 72];          // [d][s], pad 72 (144B rows, 16B aligned)
        #pragma unroll
        for (int mb = 0; mb < 2; ++mb)
            #pragma unroll
            for (int nb = 0; nb < 2; ++nb) {
                int rl_ = wr + mb * 16 + (lane >> 4) * 4;
                int cl = wc + nb * 16 + fr;
                float bv = bias[n0 + cl];
                #pragma unroll
                for (int r = 0; r < 4; ++r)
                    Cs[cl * 72 + rl_ + r] = f2bf(acc[mb][nb][r] + bv);
            }
        __syncthreads();
        const int b = m0 >> 11;                 // 2048 rows per batch
        const int s_base = m0 & 2047;
        const int h = blockIdx.x;               // one head per n-tile
        short* Vt = (short*)C;
        #pragma unroll
        for (int p = 0; p < 2; ++p) {
            int id = t + p * 256;
            int d = id >> 3, c = id & 7;
            bf16x8 v = *(const bf16x8*)(Cs + d * 72 + c * 8);
            *(bf16x8*)(Vt + ((size_t)((b * 16 + h) * 64 + d)) * S_ + s_base + c * 8) = v;
        }
    } else {
        #pragma unroll
        for (int mb = 0; mb < 2; ++mb)
            #pragma unroll
            for (int nb = 0; nb < 2; ++nb) {
                int grow = m0 + wr + mb * 16 + (lane >> 4) * 4;
                int gcol = n0 + wc + nb * 16 + fr;
                float bv = bias[gcol];
                #pragma unroll
                for (int r = 0; r < 4; ++r) {
                    float v = acc[mb][nb][r] + bv;
                    if constexpr (EPI == EPI_F32)
                        ((float*)C)[(size_t)(grow + r) * N + gcol] = v;
                    else if constexpr (EPI == EPI_BF16)
                        ((short*)C)[(size_t)(grow + r) * N + gcol] = f2bf(v);
                    else
                        ((short*)C)[(size_t)(grow + r) * N + gcol] = f2bf(v * 0.125f);
                }
            }
    }
}

// ---------------- MFMA flash attention, bf16 inputs, balanced dual q-tile ----------------
// grid (NQT/2, B*H). Block handles q-tiles {bx, NQT-1-bx} -> constant 33 k-tile steps.
// Q/K: bf16 row-major [4096][1024] (head cols h*64..). Vt: bf16 [bh*64+d][S_].
// LDS tiles [64][128B]; swizzle slot^(row&7) everywhere.
__global__ __launch_bounds__(256) void attn_fwd_bf16(
    const short* __restrict__ Qb, const short* __restrict__ Kb,
    const short* __restrict__ Vtb, short* __restrict__ Ob)
{
    __shared__ short SQ[64 * 64];
    __shared__ short SK[64 * 64];
    __shared__ short SVT[64 * 64];   // rows = d, cols = j
    __shared__ short SP[64 * 64];    // rows = q, cols = j

    const int t = threadIdx.x;
    const int lane = t & 63;
    const int w = t >> 6;
    const int g = lane >> 4;
    const int fr = lane & 15;
    const int bh = blockIdx.y;
    const int b = bh >> 4;
    const int h = bh & 15;
    const int qrow_base = w * 16 + g * 4;
    const int strow = t >> 3, stsl = t & 7;            // staging: 64 rows x 8 slots
    const int stsb = strow * 128 + ((stsl ^ (strow & 7)) << 4);

    for (int pass = 0; pass < 2; ++pass) {
        const int qt = pass ? (NQT - 1 - (int)blockIdx.x) : (int)blockIdx.x;
        const int q0 = qt * 64;
        __syncthreads();   // all threads done with previous pass
        #pragma unroll
        for (int p = 0; p < 2; ++p) {
            int id = t + p * 256;
            int row = id >> 3, sl = id & 7;
            *(bf16x8*)((char*)SQ + row * 128 + ((sl ^ (row & 7)) << 4)) =
                *(const bf16x8*)(Qb + (size_t)(b * S_ + q0 + row) * D_ + h * 64 + sl * 8);
        }

        f32x4 Oacc[4] = {};
        float m4[4] = { -1e30f, -1e30f, -1e30f, -1e30f };
        float l4[4] = { 0.f, 0.f, 0.f, 0.f };

        for (int kt = 0; kt <= qt; ++kt) {
            const int k0 = kt * 64;
            __syncthreads();   // prev iteration's PV reads (and first: pre-stage)
            #pragma unroll
            for (int p = 0; p < 2; ++p) {
                int id = t + p * 256;
                int row = id >> 3, sl = id & 7;
                int sb = row * 128 + ((sl ^ (row & 7)) << 4);
                *(bf16x8*)((char*)SK + sb) =
                    *(const bf16x8*)(Kb + (size_t)(b * S_ + k0 + row) * D_ + h * 64 + sl * 8);
                *(bf16x8*)((char*)SVT + sb) =
                    *(const bf16x8*)(Vtb + (size_t)(bh * 64 + row) * S_ + k0 + sl * 8);
            }
            __syncthreads();

            // ---- QK^T ----
            f32x4 sacc[4] = {};
            #pragma unroll
            for (int ks = 0; ks < 2; ++ks) {
                int arow = w * 16 + fr;
                bf16x8 aq = *(const bf16x8*)((const char*)SQ + arow * 128 + (((g + ks * 4) ^ (arow & 7)) << 4));
                #pragma unroll
                for (int nb = 0; nb < 4; ++nb) {
                    int brow = nb * 16 + fr;
                    bf16x8 bk = *(const bf16x8*)((const char*)SK + brow * 128 + (((g + ks * 4) ^ (brow & 7)) << 4));
                    sacc[nb] = __builtin_amdgcn_mfma_f32_16x16x32_bf16(aq, bk, sacc[nb], 0, 0, 0);
                }
            }
            if (kt == qt) {
                #pragma unroll
                for (int nb = 0; nb < 4; ++nb)
                    #pragma unroll
                    for (int r = 0; r < 4; ++r)
                        if (nb * 16 + fr > qrow_base + r) sacc[nb][r] = -1e30f;
            }

            // ---- online softmax ----
            float resc[4], ps[4];
            #pragma unroll
            for (int r = 0; r < 4; ++r) {
                float rm = fmaxf(fmaxf(sacc[0][r], sacc[1][r]), fmaxf(sacc[2][r], sacc[3][r]));
                rm = fmaxf(rm, __shfl_xor(rm, 1));
                rm = fmaxf(rm, __shfl_xor(rm, 2));
                rm = fmaxf(rm, __shfl_xor(rm, 4));
                rm = fmaxf(rm, __shfl_xor(rm, 8));
                float mn = fmaxf(m4[r], rm);
                resc[r] = __expf(m4[r] - mn);
                m4[r] = mn;
                ps[r] = 0.f;
            }
            #pragma unroll
            for (int nb = 0; nb < 4; ++nb) {
                #pragma unroll
                for (int r = 0; r < 4; ++r) {
                    float pe = __expf(sacc[nb][r] - m4[r]);
                    ps[r] += pe;
                    int col = nb * 16 + fr;
                    int row = qrow_base + r;
                    int sb = row * 128 + ((((col >> 3) ^ (row & 7))) << 4) + ((col & 7) << 1);
                    *(short*)((char*)SP + sb) = f2bf(pe);
                }
            }
            #pragma unroll
            for (int r = 0; r < 4; ++r) {
                float s = ps[r];
                s += __shfl_xor(s, 1);
                s += __shfl_xor(s, 2);
                s += __shfl_xor(s, 4);
                s += __shfl_xor(s, 8);
                l4[r] = l4[r] * resc[r] + s;
            }
            #pragma unroll
            for (int nb = 0; nb < 4; ++nb)
                #pragma unroll
                for (int r = 0; r < 4; ++r)
                    Oacc[nb][r] *= resc[r];

            // ---- PV (SP rows are wave-private; no barrier) ----
            #pragma unroll
            for (int ks = 0; ks < 2; ++ks) {
                int arow = w * 16 + fr;
                bf16x8 ap = *(const bf16x8*)((const char*)SP + arow * 128 + (((g + ks * 4) ^ (arow & 7)) << 4));
                #pragma unroll
                for (int nb = 0; nb < 4; ++nb) {
                    int brow = nb * 16 + fr;   // d
                    bf16x8 bv = *(const bf16x8*)((const char*)SVT + brow * 128 + (((g + ks * 4) ^ (brow & 7)) << 4));
                    Oacc[nb] = __builtin_amdgcn_mfma_f32_16x16x32_bf16(ap, bv, Oacc[nb], 0, 0, 0);
                }
            }
        }

        // epilogue: bf16 ctx, row-major [4096][1024]
        float rl[4];
        #pragma unroll
        for (int r = 0; r < 4; ++r) rl[r] = 1.0f / l4[r];
        #pragma unroll
        for (int nb = 0; nb < 4; ++nb) {
            #pragma unroll
            for (int r = 0; r < 4; ++r) {
                int row = qrow_base + r;
                int col = nb * 16 + fr;
                Ob[(size_t)(b * S_ + q0 + row) * D_ + h * 64 + col] = f2bf(Oacc[nb][r] * rl[r]);
            }
        }
    }
}

extern "C" void kernel_launch(void* const* d_in, const int* in_sizes, int n_in,
                              void* d_out, int out_size, void* d_ws, size_t ws_size,
                              hipStream_t stream)
{
    const float* x  = (const float*)d_in[0];
    // d_in[1] = mask (causal, computed analytically)
    const float* Wq = (const float*)d_in[2];
    const float* bq = (const float*)d_in[3];
    const float* Wk = (const float*)d_in[4];
    const float* bk = (const float*)d_in[5];
    const float* Wv = (const float*)d_in[6];
    const float* bv = (const float*)d_in[7];
    const float* Wo = (const float*)d_in[8];
    const float* bo = (const float*)d_in[9];
    float* out = (float*)d_out;

    const int M = 2 * S_;                      // 4096
    const size_t MD = (size_t)M * D_;          // 4M elems
    short* xb = (short*)d_ws;                  // 8 MB
    short* Wb = xb + MD;                       // 4 x 2 MB (q,k,v,o)
    short* Qb = Wb + 4 * (size_t)D_ * D_;      // 8 MB
    short* Kb = Qb + MD;                       // 8 MB
    short* Vt = Kb + MD;                       // 8 MB  [bh*64+d][S_]
    short* Ob = Vt + MD;                       // 8 MB  -> total 48 MB

    dim3 blk(256);
    cvt_f32_bf16<<<dim3(MD / 8 / 256), blk, 0, stream>>>(x, xb, (int)(MD / 8));
    cvt_w4<<<dim3(512, 4), blk, 0, stream>>>(Wq, Wk, Wv, Wo, Wb);

    dim3 ggrid(D_ / 64, M / 64);
    gemm_bf16_nt<EPI_BF16_SCALE><<<ggrid, blk, 0, stream>>>(xb, Wb,                bq, Qb, M, D_, D_);
    gemm_bf16_nt<EPI_BF16>      <<<ggrid, blk, 0, stream>>>(xb, Wb + (size_t)D_*D_, bk, Kb, M, D_, D_);
    gemm_bf16_nt<EPI_VT>        <<<ggrid, blk, 0, stream>>>(xb, Wb + 2*(size_t)D_*D_, bv, Vt, M, D_, D_);

    dim3 agrid(NQT / 2, 2 * H_);
    attn_fwd_bf16<<<agrid, blk, 0, stream>>>(Qb, Kb, Vt, Ob);

    gemm_bf16_nt<EPI_F32><<<ggrid, blk, 0, stream>>>(Ob, Wb + 3*(size_t)D_*D_, bo, out, M, D_, D_);
}

// Round 6
// 158.138 us; speedup vs baseline: 5.4523x; 1.1282x over previous
//
#include <hip/hip_runtime.h>
#include <hip/hip_bf16.h>
#include <cmath>

#define S_ 2048
#define D_ 1024
#define H_ 16
#define HD_ 64
#define NQT 32          // S_/64 q-tiles
#define GM 4096
#define GN 1024
#define GK 1024

typedef __attribute__((ext_vector_type(4))) float f32x4;
typedef __attribute__((ext_vector_type(8))) short bf16x8;
typedef __attribute__((ext_vector_type(4))) short bf16x4;

__device__ __forceinline__ short f2bf(float f) {
    union { float f; unsigned u; } x; x.f = f;
    unsigned r = x.u + 0x7fffu + ((x.u >> 16) & 1u);  // RNE
    return (short)(r >> 16);
}
__device__ __forceinline__ short bftrunc(float f) {   // P in [0, e^8]: truncation ok
    union { float f; unsigned u; } x; x.f = f;
    return (short)(x.u >> 16);
}
__device__ __forceinline__ void gload16(const short* g, short* l) {
    __builtin_amdgcn_global_load_lds((const __attribute__((address_space(1))) void*)g,
                                     (__attribute__((address_space(3))) void*)l, 16, 0, 0);
}

// ---------------- fp32 -> bf16 converters (one-time) ----------------
__global__ __launch_bounds__(256) void cvt_f32_bf16(const float* __restrict__ src,
                                                    short* __restrict__ dst, int n8) {
    int id = blockIdx.x * 256 + threadIdx.x;
    if (id >= n8) return;
    const float* s = src + (size_t)id * 8;
    f32x4 a = *(const f32x4*)s;
    f32x4 b = *(const f32x4*)(s + 4);
    bf16x8 h;
    h[0] = f2bf(a[0]); h[1] = f2bf(a[1]); h[2] = f2bf(a[2]); h[3] = f2bf(a[3]);
    h[4] = f2bf(b[0]); h[5] = f2bf(b[1]); h[6] = f2bf(b[2]); h[7] = f2bf(b[3]);
    *(bf16x8*)(dst + (size_t)id * 8) = h;
}

__global__ __launch_bounds__(256) void cvt_w4(const float* __restrict__ w0, const float* __restrict__ w1,
                                              const float* __restrict__ w2, const float* __restrict__ w3,
                                              short* __restrict__ dst) {
    const float* src = (blockIdx.y == 0) ? w0 : (blockIdx.y == 1) ? w1 : (blockIdx.y == 2) ? w2 : w3;
    int id = blockIdx.x * 256 + threadIdx.x;
    const float* s = src + (size_t)id * 8;
    f32x4 a = *(const f32x4*)s;
    f32x4 b = *(const f32x4*)(s + 4);
    bf16x8 h;
    h[0] = f2bf(a[0]); h[1] = f2bf(a[1]); h[2] = f2bf(a[2]); h[3] = f2bf(a[3]);
    h[4] = f2bf(b[0]); h[5] = f2bf(b[1]); h[6] = f2bf(b[2]); h[7] = f2bf(b[3]);
    *(bf16x8*)(dst + (((size_t)blockIdx.y) << 20) + (size_t)id * 8) = h;
}

// ---------------- 128x128 bf16 GEMM (m97 structure) ----------------
// C[m,n] = sum_k A[m,k]*W[n,k] + bias[n]; A,W bf16 NT. M=4096,N=1024,K=1024.
// BK=64. LDS linear [128][64] bf16; global source pre-swizzled slot^(row&7) so
// swizzled ds_read_b128 frag reads are 2-way (free). global_load_lds width 16.
// 1D grid 256 blocks; XCD-affinity: xcd=bid&7 gets m-tiles xcd*4..+3 (A panels
// 4x256KB + W 2MB resident per XCD L2).
#define EPI_F32        0
#define EPI_BF16       1
#define EPI_BF16_SCALE 2
#define EPI_VT         3   // Vt[(b*16+h)*64 + d][S_]

template<int EPI>
__global__ __launch_bounds__(256) void gemm128(
    const short* __restrict__ A, const short* __restrict__ W,
    const float* __restrict__ bias, void* __restrict__ C)
{
    __shared__ short As[128 * 64];
    __shared__ short Bs[128 * 64];
    const int t = threadIdx.x;
    const int lane = t & 63;
    const int w = t >> 6;
    const int bid = blockIdx.x;
    const int xcd = bid & 7, wk = bid >> 3;
    const int m0 = (xcd * 4 + (wk & 3)) * 128;   // 32 m-tiles
    const int n0 = (wk >> 2) * 128;              // 8 n-tiles
    const int wr = (w >> 1) * 64;
    const int wc = (w & 1) * 64;
    const int fr = lane & 15;
    const int g = lane >> 4;

    // staging decomposition: per wave 4 instr x (A,B); instr covers 8 rows x 128B
    const int srow = lane >> 3;                  // 0..7 row within 8-row group
    const int gslot = (lane & 7) ^ srow;         // pre-swizzled source slot
    const int rbase = w * 32;

    f32x4 acc[4][4] = {};

    for (int kt = 0; kt < GK; kt += 64) {
        __syncthreads();
        #pragma unroll
        for (int i = 0; i < 4; ++i) {
            int row = rbase + i * 8 + srow;
            gload16(A + (size_t)(m0 + row) * GK + kt + gslot * 8, &As[(rbase + i * 8) * 64]);
            gload16(W + (size_t)(n0 + row) * GK + kt + gslot * 8, &Bs[(rbase + i * 8) * 64]);
        }
        __syncthreads();   // drains vmcnt (compiler emits vmcnt(0) before barrier)
        #pragma unroll
        for (int ks = 0; ks < 2; ++ks) {
            bf16x8 af[4], bf_[4];
            #pragma unroll
            for (int mb = 0; mb < 4; ++mb) {
                int row = wr + mb * 16 + fr;
                af[mb] = *(const bf16x8*)((const char*)As + row * 128 + (((ks * 4 + g) ^ (row & 7)) << 4));
            }
            #pragma unroll
            for (int nb = 0; nb < 4; ++nb) {
                int row = wc + nb * 16 + fr;
                bf_[nb] = *(const bf16x8*)((const char*)Bs + row * 128 + (((ks * 4 + g) ^ (row & 7)) << 4));
            }
            #pragma unroll
            for (int mb = 0; mb < 4; ++mb)
                #pragma unroll
                for (int nb = 0; nb < 4; ++nb)
                    acc[mb][nb] = __builtin_amdgcn_mfma_f32_16x16x32_bf16(
                        af[mb], bf_[nb], acc[mb][nb], 0, 0, 0);
        }
    }

    if constexpr (EPI == EPI_VT) {
        __shared__ short Cs[128 * 136];          // [n-col][m-row], pad 136
        #pragma unroll
        for (int mb = 0; mb < 4; ++mb)
            #pragma unroll
            for (int nb = 0; nb < 4; ++nb) {
                int cl = wc + nb * 16 + fr;
                int rl_ = wr + mb * 16 + g * 4;
                float bv = bias[n0 + cl];
                bf16x4 hv;
                #pragma unroll
                for (int r = 0; r < 4; ++r) hv[r] = f2bf(acc[mb][nb][r] + bv);
                *(bf16x4*)(Cs + cl * 136 + rl_) = hv;
            }
        __syncthreads();
        const int b = m0 >> 11;
        const int s_base = m0 & 2047;
        short* Vt = (short*)C;
        #pragma unroll
        for (int p = 0; p < 8; ++p) {
            int id = t + p * 256;                // 2048 = 128 cols x 16 chunks
            int cl = id >> 4, ch = id & 15;
            int n = n0 + cl;
            int h = n >> 6, d = n & 63;
            bf16x8 v = *(const bf16x8*)(Cs + cl * 136 + ch * 8);
            *(bf16x8*)(Vt + ((size_t)((b * 16 + h) * 64 + d)) * S_ + s_base + ch * 8) = v;
        }
    } else {
        #pragma unroll
        for (int mb = 0; mb < 4; ++mb)
            #pragma unroll
            for (int nb = 0; nb < 4; ++nb) {
                int grow = m0 + wr + mb * 16 + g * 4;
                int gcol = n0 + wc + nb * 16 + fr;
                float bv = bias[gcol];
                #pragma unroll
                for (int r = 0; r < 4; ++r) {
                    float v = acc[mb][nb][r] + bv;
                    if constexpr (EPI == EPI_F32)
                        ((float*)C)[(size_t)(grow + r) * GN + gcol] = v;
                    else if constexpr (EPI == EPI_BF16)
                        ((short*)C)[(size_t)(grow + r) * GN + gcol] = f2bf(v);
                    else
                        ((short*)C)[(size_t)(grow + r) * GN + gcol] = f2bf(v * 0.125f);
                }
            }
    }
}

// ---------------- MFMA flash attention ----------------
// 1D grid 1024. XCD-affinity: xcd=bid&7 owns heads bh=xcd*4..+3 (K+Vt 2MB/XCD,
// L2-resident); qt descending within XCD (longest first -> backfill).
// Defer-max (THR=8): skip O-rescale unless tile max exceeds running max by >8.
__global__ __launch_bounds__(256) void attn_fwd_bf16(
    const short* __restrict__ Qb, const short* __restrict__ Kb,
    const short* __restrict__ Vtb, short* __restrict__ Ob)
{
    __shared__ short SQ[64 * 64];
    __shared__ short SK[64 * 64];
    __shared__ short SVT[64 * 64];   // rows = d, cols = j
    __shared__ short SP[64 * 64];    // rows = q, cols = j

    const int t = threadIdx.x;
    const int lane = t & 63;
    const int w = t >> 6;
    const int g = lane >> 4;
    const int fr = lane & 15;
    const int bid = blockIdx.x;
    const int xcd = bid & 7, idx = bid >> 3;
    const int bh = xcd * 4 + (idx & 3);
    const int qt = (NQT - 1) - (idx >> 2);
    const int b = bh >> 4;
    const int h = bh & 15;
    const int q0 = qt * 64;
    const int qrow_base = w * 16 + g * 4;

    #pragma unroll
    for (int p = 0; p < 2; ++p) {
        int id = t + p * 256;
        int row = id >> 3, sl = id & 7;
        *(bf16x8*)((char*)SQ + row * 128 + ((sl ^ (row & 7)) << 4)) =
            *(const bf16x8*)(Qb + (size_t)(b * S_ + q0 + row) * D_ + h * 64 + sl * 8);
    }

    f32x4 Oacc[4] = {};
    float m4[4] = { -1e30f, -1e30f, -1e30f, -1e30f };
    float l4[4] = { 0.f, 0.f, 0.f, 0.f };

    for (int kt = 0; kt <= qt; ++kt) {
        const int k0 = kt * 64;
        __syncthreads();   // prev iteration's PV reads done (first: Q-stage)
        #pragma unroll
        for (int p = 0; p < 2; ++p) {
            int id = t + p * 256;
            int row = id >> 3, sl = id & 7;
            int sb = row * 128 + ((sl ^ (row & 7)) << 4);
            *(bf16x8*)((char*)SK + sb) =
                *(const bf16x8*)(Kb + (size_t)(b * S_ + k0 + row) * D_ + h * 64 + sl * 8);
            *(bf16x8*)((char*)SVT + sb) =
                *(const bf16x8*)(Vtb + (size_t)(bh * 64 + row) * S_ + k0 + sl * 8);
        }
        __syncthreads();

        // ---- QK^T ----
        f32x4 sacc[4] = {};
        #pragma unroll
        for (int ks = 0; ks < 2; ++ks) {
            int arow = w * 16 + fr;
            bf16x8 aq = *(const bf16x8*)((const char*)SQ + arow * 128 + (((g + ks * 4) ^ (arow & 7)) << 4));
            #pragma unroll
            for (int nb = 0; nb < 4; ++nb) {
                int brow = nb * 16 + fr;
                bf16x8 bk = *(const bf16x8*)((const char*)SK + brow * 128 + (((g + ks * 4) ^ (brow & 7)) << 4));
                sacc[nb] = __builtin_amdgcn_mfma_f32_16x16x32_bf16(aq, bk, sacc[nb], 0, 0, 0);
            }
        }
        if (kt == qt) {
            #pragma unroll
            for (int nb = 0; nb < 4; ++nb)
                #pragma unroll
                for (int r = 0; r < 4; ++r)
                    if (nb * 16 + fr > qrow_base + r) sacc[nb][r] = -1e30f;
        }

        // ---- online softmax with defer-max ----
        float resc[4], ps[4];
        bool upd = false;
        #pragma unroll
        for (int r = 0; r < 4; ++r) {
            float rm = fmaxf(fmaxf(sacc[0][r], sacc[1][r]), fmaxf(sacc[2][r], sacc[3][r]));
            rm = fmaxf(rm, __shfl_xor(rm, 1));
            rm = fmaxf(rm, __shfl_xor(rm, 2));
            rm = fmaxf(rm, __shfl_xor(rm, 4));
            rm = fmaxf(rm, __shfl_xor(rm, 8));
            if (rm > m4[r] + 8.f) {              // P bounded by e^8 otherwise
                resc[r] = __expf(m4[r] - rm);
                m4[r] = rm;
                upd = true;
            } else resc[r] = 1.f;
            ps[r] = 0.f;
        }
        #pragma unroll
        for (int nb = 0; nb < 4; ++nb) {
            #pragma unroll
            for (int r = 0; r < 4; ++r) {
                float pe = __expf(sacc[nb][r] - m4[r]);
                ps[r] += pe;
                int col = nb * 16 + fr;
                int row = qrow_base + r;
                int sb = row * 128 + ((((col >> 3) ^ (row & 7))) << 4) + ((col & 7) << 1);
                *(short*)((char*)SP + sb) = bftrunc(pe);
            }
        }
        #pragma unroll
        for (int r = 0; r < 4; ++r) {
            float s = ps[r];
            s += __shfl_xor(s, 1);
            s += __shfl_xor(s, 2);
            s += __shfl_xor(s, 4);
            s += __shfl_xor(s, 8);
            l4[r] = l4[r] * resc[r] + s;
        }
        if (upd) {
            #pragma unroll
            for (int nb = 0; nb < 4; ++nb)
                #pragma unroll
                for (int r = 0; r < 4; ++r)
                    Oacc[nb][r] *= resc[r];
        }

        // ---- PV (SP rows are wave-private; no barrier) ----
        #pragma unroll
        for (int ks = 0; ks < 2; ++ks) {
            int arow = w * 16 + fr;
            bf16x8 ap = *(const bf16x8*)((const char*)SP + arow * 128 + (((g + ks * 4) ^ (arow & 7)) << 4));
            #pragma unroll
            for (int nb = 0; nb < 4; ++nb) {
                int brow = nb * 16 + fr;   // d
                bf16x8 bv = *(const bf16x8*)((const char*)SVT + brow * 128 + (((g + ks * 4) ^ (brow & 7)) << 4));
                Oacc[nb] = __builtin_amdgcn_mfma_f32_16x16x32_bf16(ap, bv, Oacc[nb], 0, 0, 0);
            }
        }
    }

    float rl[4];
    #pragma unroll
    for (int r = 0; r < 4; ++r) rl[r] = 1.0f / l4[r];
    #pragma unroll
    for (int nb = 0; nb < 4; ++nb) {
        #pragma unroll
        for (int r = 0; r < 4; ++r) {
            int row = qrow_base + r;
            int col = nb * 16 + fr;
            Ob[(size_t)(b * S_ + q0 + row) * D_ + h * 64 + col] = f2bf(Oacc[nb][r] * rl[r]);
        }
    }
}

extern "C" void kernel_launch(void* const* d_in, const int* in_sizes, int n_in,
                              void* d_out, int out_size, void* d_ws, size_t ws_size,
                              hipStream_t stream)
{
    const float* x  = (const float*)d_in[0];
    // d_in[1] = mask (causal, computed analytically)
    const float* Wq = (const float*)d_in[2];
    const float* bq = (const float*)d_in[3];
    const float* Wk = (const float*)d_in[4];
    const float* bk = (const float*)d_in[5];
    const float* Wv = (const float*)d_in[6];
    const float* bv = (const float*)d_in[7];
    const float* Wo = (const float*)d_in[8];
    const float* bo = (const float*)d_in[9];
    float* out = (float*)d_out;

    const size_t MD = (size_t)GM * D_;
    short* xb = (short*)d_ws;                  // 8 MB
    short* Wb = xb + MD;                       // 4 x 2 MB
    short* Qb = Wb + 4 * (size_t)D_ * D_;      // 8 MB
    short* Kb = Qb + MD;                       // 8 MB
    short* Vt = Kb + MD;                       // 8 MB
    short* Ob = Vt + MD;                       // 8 MB

    dim3 blk(256);
    cvt_f32_bf16<<<dim3(MD / 8 / 256), blk, 0, stream>>>(x, xb, (int)(MD / 8));
    cvt_w4<<<dim3(512, 4), blk, 0, stream>>>(Wq, Wk, Wv, Wo, Wb);

    gemm128<EPI_BF16_SCALE><<<dim3(256), blk, 0, stream>>>(xb, Wb,                   bq, Qb);
    gemm128<EPI_BF16>      <<<dim3(256), blk, 0, stream>>>(xb, Wb + (size_t)D_*D_,   bk, Kb);
    gemm128<EPI_VT>        <<<dim3(256), blk, 0, stream>>>(xb, Wb + 2*(size_t)D_*D_, bv, Vt);

    attn_fwd_bf16<<<dim3(1024), blk, 0, stream>>>(Qb, Kb, Vt, Ob);

    gemm128<EPI_F32><<<dim3(256), blk, 0, stream>>>(Ob, Wb + 3*(size_t)D_*D_, bo, out);
}

// Round 7
// 123.347 us; speedup vs baseline: 6.9902x; 1.2821x over previous
//
#include <hip/hip_runtime.h>
#include <hip/hip_bf16.h>
#include <cmath>

#define S_ 2048
#define D_ 1024
#define H_ 16
#define HD_ 64
#define NQT 32
#define GM 4096
#define GN 1024
#define GK 1024
#define QSCALE 0.1803368801111f   // 0.125 * log2(e)
#define THR2   11.5415603f        // 8 * log2(e)

typedef __attribute__((ext_vector_type(4))) float f32x4;
typedef __attribute__((ext_vector_type(8))) short bf16x8;
typedef __attribute__((ext_vector_type(4))) short bf16x4;

__device__ __forceinline__ short f2bf(float f) {
    union { float f; unsigned u; } x; x.f = f;
    unsigned r = x.u + 0x7fffu + ((x.u >> 16) & 1u);  // RNE
    return (short)(r >> 16);
}
__device__ __forceinline__ short bftrunc(float f) {   // P in [0, 2^11.6]: truncation ok
    union { float f; unsigned u; } x; x.f = f;
    return (short)(x.u >> 16);
}
__device__ __forceinline__ void gload16(const short* g, short* l) {
    __builtin_amdgcn_global_load_lds((const __attribute__((address_space(1))) void*)g,
                                     (__attribute__((address_space(3))) void*)l, 16, 0, 0);
}

// ---------------- one-shot fp32->bf16 convert (x + 4 W) ----------------
__global__ __launch_bounds__(256) void cvt_all(
    const float* __restrict__ x,
    const float* __restrict__ w0, const float* __restrict__ w1,
    const float* __restrict__ w2, const float* __restrict__ w3,
    short* __restrict__ xb, short* __restrict__ Wb)
{
    const int bid = blockIdx.x;        // 0..2047 x ; 2048..4095 W (512 each)
    const float* src; short* dst; int loc;
    if (bid < 2048) { src = x; dst = xb; loc = bid; }
    else {
        int wsel = (bid - 2048) >> 9, wb = (bid - 2048) & 511;
        src = wsel == 0 ? w0 : wsel == 1 ? w1 : wsel == 2 ? w2 : w3;
        dst = Wb + ((size_t)wsel << 20);
        loc = wb;
    }
    int id = loc * 256 + threadIdx.x;
    const float* s = src + (size_t)id * 8;
    f32x4 a = *(const f32x4*)s;
    f32x4 b = *(const f32x4*)(s + 4);
    bf16x8 h;
    h[0] = f2bf(a[0]); h[1] = f2bf(a[1]); h[2] = f2bf(a[2]); h[3] = f2bf(a[3]);
    h[4] = f2bf(b[0]); h[5] = f2bf(b[1]); h[6] = f2bf(b[2]); h[7] = f2bf(b[3]);
    *(bf16x8*)(dst + (size_t)id * 8) = h;
}

// ---------------- fused QKV GEMM: 128x128 tile, N'=3072, 768 blocks (3/CU) ----------------
// Epilogue by n-segment: 0 -> Qb (bf16, *QSCALE), 1 -> Kb (bf16), 2 -> Vt (per-head transpose).
__global__ __launch_bounds__(256) void gemm_qkv(
    const short* __restrict__ A, const short* __restrict__ W3,
    const float* __restrict__ bq, const float* __restrict__ bk, const float* __restrict__ bv,
    short* __restrict__ Qb, short* __restrict__ Kb, short* __restrict__ Vt)
{
    __shared__ short SMEM[17408];           // As[8192] Bs[8192] | Cs[17408] (aliased, 34816B)
    short* As = SMEM;
    short* Bs = SMEM + 8192;
    const int t = threadIdx.x, lane = t & 63, w = t >> 6;
    const int bid = blockIdx.x;
    const int xcd = bid & 7, idx = bid >> 3;   // 96 per XCD
    const int ntile = idx % 24, mloc = idx / 24;
    const int m0 = (xcd * 4 + mloc) * 128;
    const int n0g = ntile * 128;               // 0..2944
    const int wr = (w >> 1) * 64, wc = (w & 1) * 64;
    const int fr = lane & 15, g = lane >> 4;
    const int srow = lane >> 3;
    const int gslot = (lane & 7) ^ srow;       // pre-swizzled source slot (rule 21)
    const int rbase = w * 32;

    f32x4 acc[4][4] = {};

    for (int kt = 0; kt < GK; kt += 64) {
        __syncthreads();
        #pragma unroll
        for (int i = 0; i < 4; ++i) {
            int row = rbase + i * 8 + srow;
            gload16(A  + (size_t)(m0 + row) * GK + kt + gslot * 8, &As[(rbase + i * 8) * 64]);
            gload16(W3 + (size_t)(n0g + row) * GK + kt + gslot * 8, &Bs[(rbase + i * 8) * 64]);
        }
        __syncthreads();
        #pragma unroll
        for (int ks = 0; ks < 2; ++ks) {
            bf16x8 af[4], bf_[4];
            #pragma unroll
            for (int mb = 0; mb < 4; ++mb) {
                int row = wr + mb * 16 + fr;
                af[mb] = *(const bf16x8*)((const char*)As + row * 128 + (((ks * 4 + g) ^ (row & 7)) << 4));
            }
            #pragma unroll
            for (int nb = 0; nb < 4; ++nb) {
                int row = wc + nb * 16 + fr;
                bf_[nb] = *(const bf16x8*)((const char*)Bs + row * 128 + (((ks * 4 + g) ^ (row & 7)) << 4));
            }
            #pragma unroll
            for (int mb = 0; mb < 4; ++mb)
                #pragma unroll
                for (int nb = 0; nb < 4; ++nb)
                    acc[mb][nb] = __builtin_amdgcn_mfma_f32_16x16x32_bf16(
                        af[mb], bf_[nb], acc[mb][nb], 0, 0, 0);
        }
    }

    const int seg = n0g >> 10, nn = n0g & 1023;
    if (seg == 2) {                            // V: transpose to Vt[(b*16+h)*64+d][S_]
        __syncthreads();                       // all waves done reading As/Bs (alias Cs)
        short* Cs = SMEM;                      // [128 col][136 pad] of m-rows
        #pragma unroll
        for (int mb = 0; mb < 4; ++mb)
            #pragma unroll
            for (int nb = 0; nb < 4; ++nb) {
                int cl = wc + nb * 16 + fr;
                int rl_ = wr + mb * 16 + g * 4;
                float bvv = bv[nn + cl];
                bf16x4 hv;
                #pragma unroll
                for (int r = 0; r < 4; ++r) hv[r] = f2bf(acc[mb][nb][r] + bvv);
                *(bf16x4*)(Cs + cl * 136 + rl_) = hv;
            }
        __syncthreads();
        const int b = m0 >> 11;
        const int s_base = m0 & 2047;
        #pragma unroll
        for (int p = 0; p < 8; ++p) {
            int id = t + p * 256;              // 2048 = 128 cols x 16 chunks
            int cl = id >> 4, ch = id & 15;
            int n = nn + cl;
            int h = n >> 6, d = n & 63;
            bf16x8 v = *(const bf16x8*)(Cs + cl * 136 + ch * 8);
            *(bf16x8*)(Vt + ((size_t)((b * 16 + h) * 64 + d)) * S_ + s_base + ch * 8) = v;
        }
    } else {
        const float* bp = seg ? bk : bq;
        short* dst = seg ? Kb : Qb;
        const float sc = seg ? 1.0f : QSCALE;
        #pragma unroll
        for (int mb = 0; mb < 4; ++mb)
            #pragma unroll
            for (int nb = 0; nb < 4; ++nb) {
                int grow = m0 + wr + mb * 16 + g * 4;
                int gcol = nn + wc + nb * 16 + fr;
                float bvv = bp[gcol];
                #pragma unroll
                for (int r = 0; r < 4; ++r)
                    dst[(size_t)(grow + r) * GN + gcol] = f2bf((acc[mb][nb][r] + bvv) * sc);
            }
    }
}

// ---------------- O-proj GEMM: 128x128, dbuf 2-phase prefetch (256 blocks, 1/CU) ----------------
__global__ __launch_bounds__(256) void gemm_o(
    const short* __restrict__ A, const short* __restrict__ W,
    const float* __restrict__ bias, float* __restrict__ C)
{
    __shared__ short As[2][8192];
    __shared__ short Bs[2][8192];
    const int t = threadIdx.x, lane = t & 63, w = t >> 6;
    const int bid = blockIdx.x;
    const int xcd = bid & 7, wk = bid >> 3;
    const int m0 = (xcd * 4 + (wk & 3)) * 128;
    const int n0 = (wk >> 2) * 128;
    const int wr = (w >> 1) * 64, wc = (w & 1) * 64;
    const int fr = lane & 15, g = lane >> 4;
    const int srow = lane >> 3;
    const int gslot = (lane & 7) ^ srow;
    const int rbase = w * 32;

    f32x4 acc[4][4] = {};

    // prologue: stage K-step 0 into buf 0
    #pragma unroll
    for (int i = 0; i < 4; ++i) {
        int row = rbase + i * 8 + srow;
        gload16(A + (size_t)(m0 + row) * GK + gslot * 8, &As[0][(rbase + i * 8) * 64]);
        gload16(W + (size_t)(n0 + row) * GK + gslot * 8, &Bs[0][(rbase + i * 8) * 64]);
    }
    __syncthreads();

    int cur = 0;
    for (int t64 = 0; t64 < 16; ++t64) {
        if (t64 < 15) {                        // issue next-tile loads BEFORE compute
            int kt = (t64 + 1) * 64;
            #pragma unroll
            for (int i = 0; i < 4; ++i) {
                int row = rbase + i * 8 + srow;
                gload16(A + (size_t)(m0 + row) * GK + kt + gslot * 8, &As[cur ^ 1][(rbase + i * 8) * 64]);
                gload16(W + (size_t)(n0 + row) * GK + kt + gslot * 8, &Bs[cur ^ 1][(rbase + i * 8) * 64]);
            }
        }
        #pragma unroll
        for (int ks = 0; ks < 2; ++ks) {
            bf16x8 af[4], bf_[4];
            #pragma unroll
            for (int mb = 0; mb < 4; ++mb) {
                int row = wr + mb * 16 + fr;
                af[mb] = *(const bf16x8*)((const char*)&As[cur][0] + row * 128 + (((ks * 4 + g) ^ (row & 7)) << 4));
            }
            #pragma unroll
            for (int nb = 0; nb < 4; ++nb) {
                int row = wc + nb * 16 + fr;
                bf_[nb] = *(const bf16x8*)((const char*)&Bs[cur][0] + row * 128 + (((ks * 4 + g) ^ (row & 7)) << 4));
            }
            #pragma unroll
            for (int mb = 0; mb < 4; ++mb)
                #pragma unroll
                for (int nb = 0; nb < 4; ++nb)
                    acc[mb][nb] = __builtin_amdgcn_mfma_f32_16x16x32_bf16(
                        af[mb], bf_[nb], acc[mb][nb], 0, 0, 0);
        }
        __syncthreads();                       // drains prefetch vmcnt AFTER the MFMAs
        cur ^= 1;
    }

    #pragma unroll
    for (int mb = 0; mb < 4; ++mb)
        #pragma unroll
        for (int nb = 0; nb < 4; ++nb) {
            int grow = m0 + wr + mb * 16 + g * 4;
            int gcol = n0 + wc + nb * 16 + fr;
            float bvv = bias[gcol];
            #pragma unroll
            for (int r = 0; r < 4; ++r)
                C[(size_t)(grow + r) * GN + gcol] = acc[mb][nb][r] + bvv;
        }
}

// ---------------- MFMA flash attention, swapped-QK^T scalar softmax ----------------
// S^T = mfma(K,Q): lane owns q-row (w*16 + lane&15); holds k = nb*16 + (lane>>4)*4 + r.
// Softmax: in-register + 4 shfl (xor 16,32). exp2-space (QSCALE folds log2e).
// PV: O^T = mfma(V^T-frag, P^T-frag) -> lane owns same q-row, d = nbd*16+(lane>>4)*4+r.
__global__ __launch_bounds__(256) void attn_fwd_bf16(
    const short* __restrict__ Qb, const short* __restrict__ Kb,
    const short* __restrict__ Vtb, short* __restrict__ Ob)
{
    __shared__ short SQ[4096], SK[4096], SVT[4096], SP[4096];
    const int t = threadIdx.x, lane = t & 63, w = t >> 6;
    const int g = lane >> 4, fr = lane & 15;
    const int bid = blockIdx.x;
    const int xcd = bid & 7, idx = bid >> 3;
    const int bh = xcd * 4 + (idx & 3);        // 4 heads per XCD (K+Vt L2-resident)
    const int qt = (NQT - 1) - (idx >> 2);     // longest first
    const int b = bh >> 4, h = bh & 15;
    const int q0 = qt * 64;
    const int qown = w * 16 + fr;              // this lane's q row (local)
    const int qsw = qown & 7;

    #pragma unroll
    for (int p = 0; p < 2; ++p) {
        int id = t + p * 256;
        int row = id >> 3, sl = id & 7;
        *(bf16x8*)((char*)SQ + row * 128 + ((sl ^ (row & 7)) << 4)) =
            *(const bf16x8*)(Qb + (size_t)(b * S_ + q0 + row) * D_ + h * 64 + sl * 8);
    }

    f32x4 Oacc[4] = {};
    float m2 = -1e30f, l = 0.f;

    for (int kt = 0; kt <= qt; ++kt) {
        const int k0 = kt * 64;
        __syncthreads();
        #pragma unroll
        for (int p = 0; p < 2; ++p) {
            int id = t + p * 256;
            int row = id >> 3, sl = id & 7;
            int sb = row * 128 + ((sl ^ (row & 7)) << 4);
            *(bf16x8*)((char*)SK + sb) =
                *(const bf16x8*)(Kb + (size_t)(b * S_ + k0 + row) * D_ + h * 64 + sl * 8);
            *(bf16x8*)((char*)SVT + sb) =
                *(const bf16x8*)(Vtb + (size_t)(bh * 64 + row) * S_ + k0 + sl * 8);
        }
        __syncthreads();

        // ---- S^T = K * Q^T ----
        f32x4 sacc[4] = {};
        #pragma unroll
        for (int ks = 0; ks < 2; ++ks) {
            bf16x8 qf = *(const bf16x8*)((const char*)SQ + qown * 128 + (((ks * 4 + g) ^ qsw) << 4));
            #pragma unroll
            for (int nb = 0; nb < 4; ++nb) {
                int krow = nb * 16 + fr;
                bf16x8 kf = *(const bf16x8*)((const char*)SK + krow * 128 + (((ks * 4 + g) ^ (krow & 7)) << 4));
                sacc[nb] = __builtin_amdgcn_mfma_f32_16x16x32_bf16(kf, qf, sacc[nb], 0, 0, 0);
            }
        }
        if (kt == qt) {                        // causal: k_local > q_local
            #pragma unroll
            for (int nb = 0; nb < 4; ++nb)
                #pragma unroll
                for (int r = 0; r < 4; ++r)
                    if (nb * 16 + g * 4 + r > qown) sacc[nb][r] = -1e30f;
        }

        // ---- scalar online softmax (lane owns one row) ----
        float rm = -1e30f;
        #pragma unroll
        for (int nb = 0; nb < 4; ++nb)
            #pragma unroll
            for (int r = 0; r < 4; ++r) rm = fmaxf(rm, sacc[nb][r]);
        rm = fmaxf(rm, __shfl_xor(rm, 16));
        rm = fmaxf(rm, __shfl_xor(rm, 32));

        if (rm > m2 + THR2) {                  // defer-max (T13)
            float resc = exp2f(m2 - rm);
            m2 = rm;
            l *= resc;
            #pragma unroll
            for (int nb = 0; nb < 4; ++nb)
                #pragma unroll
                for (int r = 0; r < 4; ++r) Oacc[nb][r] *= resc;
        }

        float ps = 0.f;
        #pragma unroll
        for (int nb = 0; nb < 4; ++nb) {
            bf16x4 pk;
            #pragma unroll
            for (int r = 0; r < 4; ++r) {
                float pe = exp2f(sacc[nb][r] - m2);
                ps += pe;
                pk[r] = bftrunc(pe);
            }
            int k = nb * 16 + g * 4;           // 4 contiguous k -> one b64 store
            int sb = qown * 128 + ((((k >> 3) ^ qsw)) << 4) + ((k & 7) << 1);
            *(bf16x4*)((char*)SP + sb) = pk;
        }
        ps += __shfl_xor(ps, 16);
        ps += __shfl_xor(ps, 32);
        l += ps;

        // ---- PV: O^T += V^T * P^T (SP wave-private; same-wave DS order suffices) ----
        #pragma unroll
        for (int ks = 0; ks < 2; ++ks) {
            bf16x8 pf = *(const bf16x8*)((const char*)SP + qown * 128 + (((ks * 4 + g) ^ qsw) << 4));
            #pragma unroll
            for (int nbd = 0; nbd < 4; ++nbd) {
                int drow = nbd * 16 + fr;
                bf16x8 vf = *(const bf16x8*)((const char*)SVT + drow * 128 + (((ks * 4 + g) ^ (drow & 7)) << 4));
                Oacc[nbd] = __builtin_amdgcn_mfma_f32_16x16x32_bf16(vf, pf, Oacc[nbd], 0, 0, 0);
            }
        }
    }

    const float rl = 1.f / l;
    #pragma unroll
    for (int nbd = 0; nbd < 4; ++nbd)
        #pragma unroll
        for (int r = 0; r < 4; ++r) {
            int d = nbd * 16 + g * 4 + r;
            Ob[(size_t)(b * S_ + q0 + qown) * D_ + h * 64 + d] = f2bf(Oacc[nbd][r] * rl);
        }
}

extern "C" void kernel_launch(void* const* d_in, const int* in_sizes, int n_in,
                              void* d_out, int out_size, void* d_ws, size_t ws_size,
                              hipStream_t stream)
{
    const float* x  = (const float*)d_in[0];
    // d_in[1] = mask (causal, computed analytically)
    const float* Wq = (const float*)d_in[2];
    const float* bq = (const float*)d_in[3];
    const float* Wk = (const float*)d_in[4];
    const float* bk = (const float*)d_in[5];
    const float* Wv = (const float*)d_in[6];
    const float* bv = (const float*)d_in[7];
    const float* Wo = (const float*)d_in[8];
    const float* bo = (const float*)d_in[9];
    float* out = (float*)d_out;

    const size_t MD = (size_t)GM * D_;
    short* xb = (short*)d_ws;                  // 8 MB
    short* Wb = xb + MD;                       // 4 x 2 MB (q,k,v,o rows 0..4095)
    short* Qb = Wb + 4 * (size_t)D_ * D_;      // 8 MB
    short* Kb = Qb + MD;                       // 8 MB
    short* Vt = Kb + MD;                       // 8 MB
    short* Ob = Vt + MD;                       // 8 MB

    dim3 blk(256);
    cvt_all<<<dim3(4096), blk, 0, stream>>>(x, Wq, Wk, Wv, Wo, xb, Wb);
    gemm_qkv<<<dim3(768), blk, 0, stream>>>(xb, Wb, bq, bk, bv, Qb, Kb, Vt);
    attn_fwd_bf16<<<dim3(1024), blk, 0, stream>>>(Qb, Kb, Vt, Ob);
    gemm_o<<<dim3(256), blk, 0, stream>>>(Ob, Wb + 3 * (size_t)D_ * D_, bo, out);
}